// Round 14
// baseline (83.187 us; speedup 1.0000x reference)
//
#include <hip/hip_runtime.h>
#include <hip/hip_bf16.h>

// MMD loss, MI355X. Round 14: best-known components, minus one launch.
//  - prep: R13's coalesced LDS-transpose prep (512 blocks), emits R9's 512B
//    fragment-major fp8 layout; also zeroes the completion counter.
//  - gram: R9 exactly (depth-4 ping-pong direct loads, skip-exp epilogue,
//    analytic diagonal, symmetry, 2080 blocks) + fused final reduce via
//    last-block-done (agent-scope atomics; deterministic: unique last block
//    sums bout in fixed index order).
//  Rationale: 10 structural variants all hit a ~37-41us gram wall with all
//  pipes idle; last untested cost is launch/drain count (3 dispatches -> 2).
//
// ws layout: [sfb | tfb | x2s | x2t | wv | bout(NT) | counter(int)]

typedef float f32x4 __attribute__((ext_vector_type(4)));
typedef unsigned int u32x4 __attribute__((ext_vector_type(4)));

#define D 256  // feature dim

// f32 -> OCP e4m3fn, RNE, FTZ on subnormals (|x|<2^-6 -> 0; harmless here).
static __device__ __forceinline__ unsigned int f32_to_e4m3(float f) {
    unsigned int u = __float_as_uint(f);
    unsigned int sg = (u >> 24) & 0x80;
    unsigned int um = u & 0x7FFFFFFF;
    unsigned int r = um + 0x0007FFFF + ((um >> 20) & 1);  // RNE at 3 mant bits
    int e8 = (int)((r >> 23) & 0xFF) - 127 + 7;
    unsigned int m8 = (r >> 20) & 7;
    if (e8 <= 0) return sg;                                // flush to zero
    if (e8 > 15 || (e8 == 15 && m8 == 7)) return sg | 0x7E;  // clamp to 448
    return sg | ((unsigned)e8 << 3) | m8;
}

// Fragment-major fp8 layout: row-group g (16 rows), K-step s (32 k).
// Fragment (g,s) = 512 B at g*4096 + s*512; lane l = (r&15)+16*((k>>3)&3)
// holds bytes j = k&7 at +l*8.

// One block per 16-row group: coalesced f32 load, convert, LDS transpose,
// one coalesced 16B store per thread. Block 0 zeroes the counter.
__global__ __launch_bounds__(256) void prep_kernel(
    const float* __restrict__ sf, const float* __restrict__ tf,
    const int* __restrict__ lbl, const float* __restrict__ cw,
    unsigned char* __restrict__ sfb, unsigned char* __restrict__ tfb,
    float* __restrict__ x2s, float* __restrict__ x2t,
    float* __restrict__ wv, int* __restrict__ counter, int ns)
{
    __shared__ unsigned int ldsb[1024];  // 4096 B staging

    int gb = blockIdx.x;
    int nsg = ns >> 4;
    bool is_src = gb < nsg;
    int gloc = is_src ? gb : gb - nsg;
    const float* src = (is_src ? sf : tf) + (size_t)gloc * 16 * D;
    unsigned char* dstb = (is_src ? sfb : tfb) + (size_t)gloc * 4096;

    int tid = threadIdx.x;
    int l = tid & 63;
    int w = tid >> 6;

    if (gb == 0 && tid == 0)
        __hip_atomic_store(counter, 0, __ATOMIC_RELAXED,
                           __HIP_MEMORY_SCOPE_AGENT);

    if (is_src && tid < 16) {
        int r = gloc * 16 + tid;
        wv[r] = cw[lbl[r]];
    }

    #pragma unroll
    for (int p = 0; p < 4; ++p) {
        int row = 4 * p + w;             // local row 0..15
        float4 v = *(const float4*)(src + row * D + l * 4);
        unsigned int packed = f32_to_e4m3(v.x)
                            | (f32_to_e4m3(v.y) << 8)
                            | (f32_to_e4m3(v.z) << 16)
                            | (f32_to_e4m3(v.w) << 24);
        int s  = l >> 3;
        int kg = (l >> 1) & 3;
        int off = s * 512 + (row + 16 * kg) * 8 + (l & 1) * 4;
        ldsb[off >> 2] = packed;

        float ps = v.x * v.x + v.y * v.y + v.z * v.z + v.w * v.w;
        #pragma unroll
        for (int o = 32; o; o >>= 1) ps += __shfl_xor(ps, o);
        if (l == 0) {
            int gr = gloc * 16 + row;
            if (is_src) x2s[gr] = ps; else x2t[gr] = ps;
        }
    }
    __syncthreads();
    u32x4 val = ((const u32x4*)ldsb)[tid];
    __builtin_nontemporal_store(val, ((u32x4*)dstb) + tid);
}

// Fused gram + final reduce. Grid = tri(ti_s)+tri(ti_t)+ti_s*ti_t = 2080.
//   mode 0: Kss weighted, symmetric, DIAG EXCLUDED (analytic in reduce)
//   mode 1: Ktt plain sum, symmetric, DIAG EXCLUDED
//   mode 2: Kst row-weighted, full
// Block 256 thr = 4 waves (2x2), tile 128x128, wave tile 64x64, acc[4][4].
__global__ __launch_bounds__(256, 3) void gram_kernel(
    const unsigned char* __restrict__ sfb, const unsigned char* __restrict__ tfb,
    const float* __restrict__ x2s, const float* __restrict__ x2t,
    const float* __restrict__ wv, float* __restrict__ bout,
    int* __restrict__ counter, float* __restrict__ out,
    int ti_s, int ti_t)
{
    int tri_s = ti_s * (ti_s + 1) / 2;
    int tri_t = ti_t * (ti_t + 1) / 2;
    int NT = tri_s + tri_t + ti_s * ti_t;
    int blk = blockIdx.x;

    int mode, bi, bj;
    const unsigned char *X, *Y;
    const float *x2xp, *x2yp;
    if (blk < tri_s + tri_t) {
        int T, idx;
        if (blk < tri_s) { mode = 0; idx = blk; T = ti_s; X = sfb; Y = sfb; x2xp = x2s; x2yp = x2s; }
        else { mode = 1; idx = blk - tri_s; T = ti_t; X = tfb; Y = tfb; x2xp = x2t; x2yp = x2t; }
        bi = (int)((2.0f * T + 1.0f -
                    sqrtf((float)((2 * T + 1) * (2 * T + 1) - 8 * idx))) * 0.5f);
        if (bi < 0) bi = 0;
        if (bi > T - 1) bi = T - 1;
        int base = bi * (2 * T - bi + 1) / 2;
        while (base > idx) { --bi; base = bi * (2 * T - bi + 1) / 2; }
        while (idx >= base + (T - bi)) { base += (T - bi); ++bi; }
        bj = bi + (idx - base);
    } else {
        int idx = blk - tri_s - tri_t;
        mode = 2; bi = idx / ti_t; bj = idx % ti_t;
        X = sfb; Y = tfb; x2xp = x2s; x2yp = x2t;
    }
    float factor = (mode != 2 && bi != bj) ? 2.0f : 1.0f;

    int wid = threadIdx.x >> 6;
    int lane = threadIdx.x & 63;
    int wr = wid >> 1, wc = wid & 1;
    int R0 = bi * 128 + wr * 64;
    int C0 = bj * 128 + wc * 64;

    const unsigned char* XA = X + (size_t)(R0 >> 4) * 4096 + lane * 8;
    const unsigned char* YB = Y + (size_t)(C0 >> 4) * 4096 + lane * 8;

    f32x4 acc[4][4] = {};
    long af[4][4], bf_[4][4];
    #pragma unroll
    for (int sp = 0; sp < 3; ++sp) {
        #pragma unroll
        for (int m = 0; m < 4; ++m) {
            af[sp][m]  = *(const long*)(XA + (size_t)(m * 8 + sp) * 512);
            bf_[sp][m] = *(const long*)(YB + (size_t)(m * 8 + sp) * 512);
        }
    }
    #pragma unroll
    for (int s = 0; s < 8; ++s) {
        const int cur = s & 3;
        if (s < 5) {
            const int pf = (s + 3) & 3;
            #pragma unroll
            for (int m = 0; m < 4; ++m) {
                af[pf][m]  = *(const long*)(XA + (size_t)(m * 8 + s + 3) * 512);
                bf_[pf][m] = *(const long*)(YB + (size_t)(m * 8 + s + 3) * 512);
            }
        }
        #pragma unroll
        for (int m = 0; m < 4; ++m)
            #pragma unroll
            for (int n = 0; n < 4; ++n)
                acc[m][n] = __builtin_amdgcn_mfma_f32_16x16x32_fp8_fp8(
                    af[cur][m], bf_[cur][n], acc[m][n], 0, 0, 0);
    }

    // Skip-exp epilogue: all sq>=180 -> K underflows f32 -> contributes 0.
    int crow = (lane >> 4) * 4;
    int ccol = lane & 15;
    float x2yc[4];
    #pragma unroll
    for (int n = 0; n < 4; ++n) x2yc[n] = x2yp[C0 + 16 * n + ccol];

    float s = 0.0f;
    #pragma unroll
    for (int m = 0; m < 4; ++m) {
        #pragma unroll
        for (int r = 0; r < 4; ++r) {
            int gr = R0 + 16 * m + crow + r;
            float rx2 = x2xp[gr];
            float sq0 = fmaxf(rx2 + x2yc[0] - 2.0f * acc[m][0][r], 0.0f);
            float sq1 = fmaxf(rx2 + x2yc[1] - 2.0f * acc[m][1][r], 0.0f);
            float sq2 = fmaxf(rx2 + x2yc[2] - 2.0f * acc[m][2][r], 0.0f);
            float sq3 = fmaxf(rx2 + x2yc[3] - 2.0f * acc[m][3][r], 0.0f);
            float mn = fminf(fminf(sq0, sq1), fminf(sq2, sq3));
            if (__any(mn < 180.0f)) {   // rare: near-duplicate rows only
                float rw = (mode != 1) ? wv[gr] : 1.0f;
                float sqv[4] = {sq0, sq1, sq2, sq3};
                #pragma unroll
                for (int n = 0; n < 4; ++n) {
                    int gc = C0 + 16 * n + ccol;
                    float K = __expf(-0.5f * sqv[n]);
                    if (mode != 2 && gr == gc) K = 0.0f;  // diag analytic
                    float wf = (mode == 0) ? rw * wv[gc] : rw;
                    s += wf * K;
                }
            }
        }
    }
    s *= factor;
    #pragma unroll
    for (int o = 32; o; o >>= 1) s += __shfl_xor(s, o);

    __shared__ float bsum[4];
    __shared__ int tks;
    if (lane == 0) bsum[wid] = s;
    __syncthreads();
    if (threadIdx.x == 0) {
        float v = (bsum[0] + bsum[1]) + (bsum[2] + bsum[3]);
        __hip_atomic_store(&bout[blk], v, __ATOMIC_RELEASE,
                           __HIP_MEMORY_SCOPE_AGENT);
        tks = __hip_atomic_fetch_add(counter, 1, __ATOMIC_ACQ_REL,
                                     __HIP_MEMORY_SCOPE_AGENT);
    }
    __syncthreads();
    if (tks != NT - 1) return;

    // ---- last block: final reduce (deterministic fixed-order sums) ----
    int tid = threadIdx.x;
    int ns = ti_s * 128, ntr = ti_t * 128;
    float n = 0.0f, dsq = 0.0f, a0 = 0.0f, a1 = 0.0f, a2 = 0.0f;
    for (int i = tid; i < ns; i += 256) {
        float w = wv[i];
        n += w; dsq += w * w;
    }
    for (int i = tid; i < NT; i += 256) {
        float v = __hip_atomic_load(&bout[i], __ATOMIC_ACQUIRE,
                                    __HIP_MEMORY_SCOPE_AGENT);
        if (i < tri_s) a0 += v;
        else if (i < tri_s + tri_t) a1 += v;
        else a2 += v;
    }
    #pragma unroll
    for (int o = 32; o; o >>= 1) {
        n   += __shfl_xor(n, o);
        dsq += __shfl_xor(dsq, o);
        a0  += __shfl_xor(a0, o);
        a1  += __shfl_xor(a1, o);
        a2  += __shfl_xor(a2, o);
    }
    __shared__ float ln[4], ld[4], l0[4], l1[4], l2[4];
    if (lane == 0) { ln[wid] = n; ld[wid] = dsq; l0[wid] = a0; l1[wid] = a1; l2[wid] = a2; }
    __syncthreads();
    if (tid == 0) {
        float N = 0, DQ = 0, A0 = 0, A1 = 0, A2 = 0;
        #pragma unroll
        for (int i = 0; i < 4; ++i) {
            N += ln[i]; DQ += ld[i]; A0 += l0[i]; A1 += l1[i]; A2 += l2[i];
        }
        float fnt = (float)ntr;
        out[0] = (A0 + DQ) / (N * N) + (A1 + fnt) / (fnt * fnt)
               - 2.0f * A2 / (N * fnt);
    }
}

extern "C" void kernel_launch(void* const* d_in, const int* in_sizes, int n_in,
                              void* d_out, int out_size, void* d_ws, size_t ws_size,
                              hipStream_t stream) {
    const float* sf = (const float*)d_in[0];
    const int* lbl = (const int*)d_in[1];
    const float* tf = (const float*)d_in[2];
    const float* cw = (const float*)d_in[3];
    float* out = (float*)d_out;

    int ns = in_sizes[1];
    int d = in_sizes[0] / ns;   // expect 256
    int nt = in_sizes[2] / d;

    char* p = (char*)d_ws;
    unsigned char* sfb = (unsigned char*)p;  p += (size_t)ns * d;
    unsigned char* tfb = (unsigned char*)p;  p += (size_t)nt * d;
    float* x2s = (float*)p;                  p += (size_t)ns * sizeof(float);
    float* x2t = (float*)p;                  p += (size_t)nt * sizeof(float);
    float* wv  = (float*)p;                  p += (size_t)ns * sizeof(float);
    int ti_s = ns / 128, ti_t = nt / 128;
    int tri_s = ti_s * (ti_s + 1) / 2;
    int tri_t = ti_t * (ti_t + 1) / 2;
    int NT = tri_s + tri_t + ti_s * ti_t;    // 2080
    float* bout = (float*)p;                 p += (size_t)NT * sizeof(float);
    int* counter = (int*)p;

    prep_kernel<<<(ns + nt) / 16, 256, 0, stream>>>(sf, tf, lbl, cw, sfb, tfb,
                                                    x2s, x2t, wv, counter, ns);

    gram_kernel<<<NT, 256, 0, stream>>>(sfb, tfb, x2s, x2t, wv, bout,
                                        counter, out, ti_s, ti_t);
}

// Round 15
// 41.412 us; speedup vs baseline: 2.0088x; 2.0088x over previous
//
#include <hip/hip_runtime.h>
#include <hip/hip_bf16.h>

// MMD loss, MI355X. Round 15: consolidation of best-known components.
//  R14's fused last-block reduce regressed 2x (per-block agent-scope
//  release/acquire fences = 2080 L2 writeback drains). Reverted.
//  - prep: R13 coalesced LDS-transpose prep (512 blocks), R9 512B layout.
//  - gram: R9 verbatim (depth-4 ping-pong direct loads, fp8 e4m3,
//    skip-exp epilogue, analytic diagonal, symmetry, 2080 blocks).
//  - reduce: R9 separate single-block kernel. No atomics anywhere.
//
// ws layout: [sfb fp8 fragmajor | tfb fp8 fragmajor | x2s | x2t | wv | bout]

typedef float f32x4 __attribute__((ext_vector_type(4)));
typedef unsigned int u32x4 __attribute__((ext_vector_type(4)));

#define D 256  // feature dim

// f32 -> OCP e4m3fn, RNE, FTZ on subnormals (|x|<2^-6 -> 0; harmless here).
static __device__ __forceinline__ unsigned int f32_to_e4m3(float f) {
    unsigned int u = __float_as_uint(f);
    unsigned int sg = (u >> 24) & 0x80;
    unsigned int um = u & 0x7FFFFFFF;
    unsigned int r = um + 0x0007FFFF + ((um >> 20) & 1);  // RNE at 3 mant bits
    int e8 = (int)((r >> 23) & 0xFF) - 127 + 7;
    unsigned int m8 = (r >> 20) & 7;
    if (e8 <= 0) return sg;                                // flush to zero
    if (e8 > 15 || (e8 == 15 && m8 == 7)) return sg | 0x7E;  // clamp to 448
    return sg | ((unsigned)e8 << 3) | m8;
}

// Fragment-major fp8 layout: row-group g (16 rows), K-step s (32 k).
// Fragment (g,s) = 512 B at g*4096 + s*512; lane l = (r&15)+16*((k>>3)&3)
// holds bytes j = k&7 at +l*8.

// One block per 16-row group: coalesced f32 load, convert, LDS transpose,
// one coalesced 16B store per thread.
__global__ __launch_bounds__(256) void prep_kernel(
    const float* __restrict__ sf, const float* __restrict__ tf,
    const int* __restrict__ lbl, const float* __restrict__ cw,
    unsigned char* __restrict__ sfb, unsigned char* __restrict__ tfb,
    float* __restrict__ x2s, float* __restrict__ x2t,
    float* __restrict__ wv, int ns)
{
    __shared__ unsigned int ldsb[1024];  // 4096 B staging

    int gb = blockIdx.x;
    int nsg = ns >> 4;
    bool is_src = gb < nsg;
    int gloc = is_src ? gb : gb - nsg;
    const float* src = (is_src ? sf : tf) + (size_t)gloc * 16 * D;
    unsigned char* dstb = (is_src ? sfb : tfb) + (size_t)gloc * 4096;

    int tid = threadIdx.x;
    int l = tid & 63;
    int w = tid >> 6;

    if (is_src && tid < 16) {
        int r = gloc * 16 + tid;
        wv[r] = cw[lbl[r]];
    }

    #pragma unroll
    for (int p = 0; p < 4; ++p) {
        int row = 4 * p + w;             // local row 0..15
        float4 v = *(const float4*)(src + row * D + l * 4);
        unsigned int packed = f32_to_e4m3(v.x)
                            | (f32_to_e4m3(v.y) << 8)
                            | (f32_to_e4m3(v.z) << 16)
                            | (f32_to_e4m3(v.w) << 24);
        int s  = l >> 3;
        int kg = (l >> 1) & 3;
        int off = s * 512 + (row + 16 * kg) * 8 + (l & 1) * 4;
        ldsb[off >> 2] = packed;

        float ps = v.x * v.x + v.y * v.y + v.z * v.z + v.w * v.w;
        #pragma unroll
        for (int o = 32; o; o >>= 1) ps += __shfl_xor(ps, o);
        if (l == 0) {
            int gr = gloc * 16 + row;
            if (is_src) x2s[gr] = ps; else x2t[gr] = ps;
        }
    }
    __syncthreads();
    u32x4 val = ((const u32x4*)ldsb)[tid];
    __builtin_nontemporal_store(val, ((u32x4*)dstb) + tid);
}

// Fused gram kernel. Grid = tri(ti_s) + tri(ti_t) + ti_s*ti_t = 2080 blocks.
//   mode 0: Kss weighted, symmetric, DIAG EXCLUDED (analytic in reduce)
//   mode 1: Ktt plain sum, symmetric, DIAG EXCLUDED
//   mode 2: Kst row-weighted, full
// Block 256 thr = 4 waves (2x2), tile 128x128, wave tile 64x64, acc[4][4].
__global__ __launch_bounds__(256, 3) void gram_kernel(
    const unsigned char* __restrict__ sfb, const unsigned char* __restrict__ tfb,
    const float* __restrict__ x2s, const float* __restrict__ x2t,
    const float* __restrict__ wv, float* __restrict__ bout,
    int ti_s, int ti_t)
{
    int tri_s = ti_s * (ti_s + 1) / 2;
    int tri_t = ti_t * (ti_t + 1) / 2;
    int blk = blockIdx.x;

    int mode, bi, bj;
    const unsigned char *X, *Y;
    const float *x2xp, *x2yp;
    if (blk < tri_s + tri_t) {
        int T, idx;
        if (blk < tri_s) { mode = 0; idx = blk; T = ti_s; X = sfb; Y = sfb; x2xp = x2s; x2yp = x2s; }
        else { mode = 1; idx = blk - tri_s; T = ti_t; X = tfb; Y = tfb; x2xp = x2t; x2yp = x2t; }
        bi = (int)((2.0f * T + 1.0f -
                    sqrtf((float)((2 * T + 1) * (2 * T + 1) - 8 * idx))) * 0.5f);
        if (bi < 0) bi = 0;
        if (bi > T - 1) bi = T - 1;
        int base = bi * (2 * T - bi + 1) / 2;
        while (base > idx) { --bi; base = bi * (2 * T - bi + 1) / 2; }
        while (idx >= base + (T - bi)) { base += (T - bi); ++bi; }
        bj = bi + (idx - base);
    } else {
        int idx = blk - tri_s - tri_t;
        mode = 2; bi = idx / ti_t; bj = idx % ti_t;
        X = sfb; Y = tfb; x2xp = x2s; x2yp = x2t;
    }
    float factor = (mode != 2 && bi != bj) ? 2.0f : 1.0f;

    int wid = threadIdx.x >> 6;
    int lane = threadIdx.x & 63;
    int wr = wid >> 1, wc = wid & 1;
    int R0 = bi * 128 + wr * 64;
    int C0 = bj * 128 + wc * 64;

    const unsigned char* XA = X + (size_t)(R0 >> 4) * 4096 + lane * 8;
    const unsigned char* YB = Y + (size_t)(C0 >> 4) * 4096 + lane * 8;

    f32x4 acc[4][4] = {};
    long af[4][4], bf_[4][4];
    #pragma unroll
    for (int sp = 0; sp < 3; ++sp) {
        #pragma unroll
        for (int m = 0; m < 4; ++m) {
            af[sp][m]  = *(const long*)(XA + (size_t)(m * 8 + sp) * 512);
            bf_[sp][m] = *(const long*)(YB + (size_t)(m * 8 + sp) * 512);
        }
    }
    #pragma unroll
    for (int s = 0; s < 8; ++s) {
        const int cur = s & 3;
        if (s < 5) {
            const int pf = (s + 3) & 3;
            #pragma unroll
            for (int m = 0; m < 4; ++m) {
                af[pf][m]  = *(const long*)(XA + (size_t)(m * 8 + s + 3) * 512);
                bf_[pf][m] = *(const long*)(YB + (size_t)(m * 8 + s + 3) * 512);
            }
        }
        #pragma unroll
        for (int m = 0; m < 4; ++m)
            #pragma unroll
            for (int n = 0; n < 4; ++n)
                acc[m][n] = __builtin_amdgcn_mfma_f32_16x16x32_fp8_fp8(
                    af[cur][m], bf_[cur][n], acc[m][n], 0, 0, 0);
    }

    // Skip-exp epilogue: all sq>=180 -> K underflows f32 -> contributes 0.
    int crow = (lane >> 4) * 4;
    int ccol = lane & 15;
    float x2yc[4];
    #pragma unroll
    for (int n = 0; n < 4; ++n) x2yc[n] = x2yp[C0 + 16 * n + ccol];

    float s = 0.0f;
    #pragma unroll
    for (int m = 0; m < 4; ++m) {
        #pragma unroll
        for (int r = 0; r < 4; ++r) {
            int gr = R0 + 16 * m + crow + r;
            float rx2 = x2xp[gr];
            float sq0 = fmaxf(rx2 + x2yc[0] - 2.0f * acc[m][0][r], 0.0f);
            float sq1 = fmaxf(rx2 + x2yc[1] - 2.0f * acc[m][1][r], 0.0f);
            float sq2 = fmaxf(rx2 + x2yc[2] - 2.0f * acc[m][2][r], 0.0f);
            float sq3 = fmaxf(rx2 + x2yc[3] - 2.0f * acc[m][3][r], 0.0f);
            float mn = fminf(fminf(sq0, sq1), fminf(sq2, sq3));
            if (__any(mn < 180.0f)) {   // rare: near-duplicate rows only
                float rw = (mode != 1) ? wv[gr] : 1.0f;
                float sqv[4] = {sq0, sq1, sq2, sq3};
                #pragma unroll
                for (int n = 0; n < 4; ++n) {
                    int gc = C0 + 16 * n + ccol;
                    float K = __expf(-0.5f * sqv[n]);
                    if (mode != 2 && gr == gc) K = 0.0f;  // diag in reduce
                    float wf = (mode == 0) ? rw * wv[gc] : rw;
                    s += wf * K;
                }
            }
        }
    }
    s *= factor;
    #pragma unroll
    for (int o = 32; o; o >>= 1) s += __shfl_xor(s, o);

    __shared__ float bsum[4];
    if (lane == 0) bsum[wid] = s;
    __syncthreads();
    if (threadIdx.x == 0)
        bout[blk] = (bsum[0] + bsum[1]) + (bsum[2] + bsum[3]);
}

// Single-block final reduce: n = sum(wv), dsq = sum(wv^2) (analytic Kss
// diag), Ktt diag = nt, three mode sums from segmented bout, combine.
__global__ __launch_bounds__(1024) void reduce_kernel(
    const float* __restrict__ wv, int ns,
    const float* __restrict__ bout, int tri_s, int tri_t, int nb,
    float* __restrict__ out, int nt)
{
    int tid = threadIdx.x;
    float n = 0.0f, dsq = 0.0f, a0 = 0.0f, a1 = 0.0f, a2 = 0.0f;
    for (int i = tid; i < ns; i += 1024) {
        float w = wv[i];
        n += w;
        dsq += w * w;
    }
    for (int i = tid; i < nb; i += 1024) {
        float v = bout[i];
        if (i < tri_s) a0 += v;
        else if (i < tri_s + tri_t) a1 += v;
        else a2 += v;
    }
    #pragma unroll
    for (int o = 32; o; o >>= 1) {
        n   += __shfl_xor(n, o);
        dsq += __shfl_xor(dsq, o);
        a0  += __shfl_xor(a0, o);
        a1  += __shfl_xor(a1, o);
        a2  += __shfl_xor(a2, o);
    }
    __shared__ float ln[16], ld[16], l0[16], l1[16], l2[16];
    int w = tid >> 6;
    if ((tid & 63) == 0) { ln[w] = n; ld[w] = dsq; l0[w] = a0; l1[w] = a1; l2[w] = a2; }
    __syncthreads();
    if (tid == 0) {
        float N = 0, DQ = 0, A0 = 0, A1 = 0, A2 = 0;
        #pragma unroll
        for (int i = 0; i < 16; ++i) {
            N += ln[i]; DQ += ld[i]; A0 += l0[i]; A1 += l1[i]; A2 += l2[i];
        }
        float fnt = (float)nt;
        out[0] = (A0 + DQ) / (N * N) + (A1 + fnt) / (fnt * fnt)
               - 2.0f * A2 / (N * fnt);
    }
}

extern "C" void kernel_launch(void* const* d_in, const int* in_sizes, int n_in,
                              void* d_out, int out_size, void* d_ws, size_t ws_size,
                              hipStream_t stream) {
    const float* sf = (const float*)d_in[0];
    const int* lbl = (const int*)d_in[1];
    const float* tf = (const float*)d_in[2];
    const float* cw = (const float*)d_in[3];
    float* out = (float*)d_out;

    int ns = in_sizes[1];
    int d = in_sizes[0] / ns;   // expect 256
    int nt = in_sizes[2] / d;

    char* p = (char*)d_ws;
    unsigned char* sfb = (unsigned char*)p;  p += (size_t)ns * d;
    unsigned char* tfb = (unsigned char*)p;  p += (size_t)nt * d;
    float* x2s = (float*)p;                  p += (size_t)ns * sizeof(float);
    float* x2t = (float*)p;                  p += (size_t)nt * sizeof(float);
    float* wv  = (float*)p;                  p += (size_t)ns * sizeof(float);
    float* bout = (float*)p;

    prep_kernel<<<(ns + nt) / 16, 256, 0, stream>>>(sf, tf, lbl, cw, sfb, tfb,
                                                    x2s, x2t, wv, ns);

    int ti_s = ns / 128, ti_t = nt / 128;
    int tri_s = ti_s * (ti_s + 1) / 2;
    int tri_t = ti_t * (ti_t + 1) / 2;
    int nblocks = tri_s + tri_t + ti_s * ti_t;   // 2080
    gram_kernel<<<nblocks, 256, 0, stream>>>(sfb, tfb, x2s, x2t, wv, bout,
                                             ti_s, ti_t);

    reduce_kernel<<<1, 1024, 0, stream>>>(wv, ns, bout, tri_s, tri_t, nblocks,
                                          out, nt);
}